// Round 12
// baseline (21.023 us; speedup 1.0000x reference)
//
#include <hip/hip_runtime.h>

// NeighborsConvolution: out[z,a,i] = sum_{b,x,j} [|r_b-r_a|<0.5] * (r_b-r_a)_x * W[x,i,j] * feat[z,b,j]
// B=8, N=1024, CIN=COUT=64.
//
// R12 = R11 intent (chunk-4 process: 4 independent feat loads per vmcnt wait)
// without writelane (builtin absent on this ROCm):
//  - Scan keeps ballot masks in wave-uniform SGPRs (R7/R10 structure).
//  - Process walks masks, collecting b's into a 4-slot pending buffer of
//    NAMED scalars (uniform selects; no runtime-indexed array -> no scratch).
//    Flush issues 4 back-to-back coalesced feat loads + uniform geo broadcast
//    diff recompute + 12 FMAs. One load-latency wait per 4 neighbors.
//  - Tail pads with b=a (diff==0 exactly -> contributes 0); order bit-identical.
//  - Single kernel, chunked swizzled W-LDS pickup + xj-split epilogue (R10).

#define BATCHSZ 8
#define NPTS 1024
#define CIN 64
#define COUT 64
#define NXJ (3 * CIN)      // 192
#define NG (NXJ / 4)       // 48 float4 groups
#define PPB 8              // points (waves) per block
#define BS (PPB * 64)      // 512
#define GPW (NG / PPB)     // 6 W-groups per wave
#define NSTEP (NPTS / 64)  // 16 ballot steps

typedef float f32x2 __attribute__((ext_vector_type(2)));

// smem layout (floats):
//  [0,3072)     geo (12KB)                 live: stage -> end of process
//  [3072,7168)  wstage / red (16KB)        live: prologue staging, then epilogue red
//  [7168,8704)  tmp[8][192] (6KB)
#define SM_RED 3072
#define SM_TMP 7168
#define SM_TOTAL 8704

__global__ __launch_bounds__(BS, 8) void neigh_conv_kernel(
    const float* __restrict__ feat,  // [B,N,CIN]
    const float* __restrict__ geom,  // [B,N,3]
    const float* __restrict__ W,     // [3,COUT,CIN]
    float* __restrict__ out)         // [B,N,COUT]
{
    const int lane = threadIdx.x & 63;
    const int wv   = threadIdx.x >> 6;
    const int p    = blockIdx.x * PPB + wv;
    const int a    = p & (NPTS - 1);
    const int z    = p >> 10;        // uniform across block (8 | 1024)

    __shared__ __align__(16) float smem[SM_TOTAL];

    // ---- stage geometry (coalesced float4) ----
    {
        const float4* src = (const float4*)(geom + (size_t)z * NPTS * 3);
        float4* dst = (float4*)smem;
        for (int k = threadIdx.x; k < NPTS * 3 / 4; k += BS)
            dst[k] = src[k];
    }

    // ---- W fragment pickup via chunked LDS staging (16KB per x-chunk) ----
    // wr[q] = { W[x][lane][4c+e], e=0..3 }  with g = 6*wv+q, x = g>>4, c = g&15
    const int g0 = wv * GPW;
    float4 wr[GPW];
    {
        const float4* w4 = (const float4*)W;          // [3][1024] float4
        float4* ws = (float4*)(smem + SM_RED);        // 1024 float4
        for (int x = 0; x < 3; ++x) {
            __syncthreads();  // x=0: geo done; x>0: prev pickups done
            // stage chunk x, XOR-rotate swizzle: k=(i*16+j4) -> i*16+((j4+i)&15)
            #pragma unroll
            for (int kk = 0; kk < 2; ++kk) {
                const int k = threadIdx.x + kk * BS;
                const int idx = (k & ~15) | ((k + (k >> 4)) & 15);
                ws[idx] = w4[x * 1024 + k];           // coalesced global read
            }
            __syncthreads();
            #pragma unroll
            for (int q = 0; q < GPW; ++q) {
                const int g = g0 + q;
                if ((g >> 4) == x) {                  // wave-uniform
                    const int c = g & 15;
                    wr[q] = ws[(lane << 4) | ((c + lane) & 15)];  // conflict-free
                }
            }
        }
    }

    const float* geo = smem;
    const float gax = geo[a * 3 + 0];
    const float gay = geo[a * 3 + 1];
    const float gaz = geo[a * 3 + 2];
    const float* fz = feat + (size_t)z * NPTS * CIN;

    // ---- scan: 16 ballot steps; masks live wave-uniform (SGPR pairs) ----
    unsigned long long masks[NSTEP];
    #pragma unroll
    for (int ss = 0; ss < NSTEP; ++ss) {
        const int b = ss * 64 + lane;
        float d2;
        {
            // Bit-exact vs numpy near boundary: no contraction, left-assoc.
            #pragma clang fp contract(off)
            const float dx = geo[b * 3 + 0] - gax;   // stride-3: conflict-free
            const float dy = geo[b * 3 + 1] - gay;
            const float dz = geo[b * 3 + 2] - gaz;
            d2 = dx * dx + dy * dy + dz * dz;
        }
        masks[ss] = __ballot(d2 < 0.25f);
    }

    // ---- process: pending-4 buffer, 4 independent feat loads per flush ----
    float acc0 = 0.f, acc1 = 0.f, acc2 = 0.f;
    int pb0 = a, pb1 = a, pb2 = a, pb3 = a;   // pending neighbor indices
    int cnt = 0;                               // wave-uniform

    auto flush4 = [&]() {
        // 4 independent coalesced loads: one vmcnt wait per 4 neighbors
        const float f0 = fz[(size_t)pb0 * CIN + lane];
        const float f1 = fz[(size_t)pb1 * CIN + lane];
        const float f2 = fz[(size_t)pb2 * CIN + lane];
        const float f3 = fz[(size_t)pb3 * CIN + lane];
        // diffs recomputed from uniform geo broadcasts (bit-identical subs;
        // pb=a pad gives exactly 0 -> zero contribution)
        const float x0 = geo[pb0 * 3 + 0] - gax, y0 = geo[pb0 * 3 + 1] - gay, z0 = geo[pb0 * 3 + 2] - gaz;
        const float x1 = geo[pb1 * 3 + 0] - gax, y1 = geo[pb1 * 3 + 1] - gay, z1 = geo[pb1 * 3 + 2] - gaz;
        const float x2 = geo[pb2 * 3 + 0] - gax, y2 = geo[pb2 * 3 + 1] - gay, z2 = geo[pb2 * 3 + 2] - gaz;
        const float x3 = geo[pb3 * 3 + 0] - gax, y3 = geo[pb3 * 3 + 1] - gay, z3 = geo[pb3 * 3 + 2] - gaz;
        acc0 = fmaf(x0, f0, acc0); acc1 = fmaf(y0, f0, acc1); acc2 = fmaf(z0, f0, acc2);
        acc0 = fmaf(x1, f1, acc0); acc1 = fmaf(y1, f1, acc1); acc2 = fmaf(z1, f1, acc2);
        acc0 = fmaf(x2, f2, acc0); acc1 = fmaf(y2, f2, acc1); acc2 = fmaf(z2, f2, acc2);
        acc0 = fmaf(x3, f3, acc0); acc1 = fmaf(y3, f3, acc1); acc2 = fmaf(z3, f3, acc2);
    };

    #pragma unroll
    for (int ss = 0; ss < NSTEP; ++ss) {
        unsigned long long mm = masks[ss];
        while (mm) {                     // wave-uniform scalar walk (no memory)
            const int src = __ffsll(mm) - 1;
            mm &= mm - 1ull;
            const int b = ss * 64 + src;
            const int c = cnt & 3;       // uniform selects into named slots
            pb0 = (c == 0) ? b : pb0;
            pb1 = (c == 1) ? b : pb1;
            pb2 = (c == 2) ? b : pb2;
            pb3 = (c == 3) ? b : pb3;
            ++cnt;
            if ((cnt & 3) == 0) flush4();
        }
    }
    // tail: pad remaining slots with a (zero contribution), flush once
    {
        const int r = cnt & 3;
        if (r != 0) {                    // wave-uniform
            if (r <= 1) pb1 = a;
            if (r <= 2) pb2 = a;
            pb3 = a;
            flush4();
        }
    }

    float* tmp = smem + SM_TMP + wv * NXJ;
    tmp[0 * CIN + lane] = acc0;
    tmp[1 * CIN + lane] = acc1;
    tmp[2 * CIN + lane] = acc2;
    __syncthreads();   // pickups done, tmp visible; red free to write

    // ---- epilogue: wave wv owns W groups [6wv,6wv+6), all 8 points ----
    float* red = smem + SM_RED;   // red[wv*8+pp][i]
    #pragma unroll
    for (int pp = 0; pp < PPB; ++pp) {
        const float4* t4 = (const float4*)(smem + SM_TMP + pp * NXJ);
        f32x2 facc = {0.f, 0.f};
        #pragma unroll
        for (int q = 0; q < GPW; ++q) {
            const float4 t = t4[g0 + q];          // uniform -> LDS broadcast
            f32x2 ta; ta.x = t.x; ta.y = t.y;
            f32x2 tb; tb.x = t.z; tb.y = t.w;
            f32x2 wa; wa.x = wr[q].x; wa.y = wr[q].y;
            f32x2 wb; wb.x = wr[q].z; wb.y = wr[q].w;
            facc = ta * wa + facc;                // v_pk_fma_f32
            facc = tb * wb + facc;
        }
        red[(wv * PPB + pp) * COUT + lane] = facc.x + facc.y;
    }
    __syncthreads();

    float o = 0.f;
    #pragma unroll
    for (int w = 0; w < PPB; ++w)
        o += red[(w * PPB + wv) * COUT + lane];   // 2 lanes/bank: free

    out[(size_t)p * COUT + lane] = o;
}

extern "C" void kernel_launch(void* const* d_in, const int* in_sizes, int n_in,
                              void* d_out, int out_size, void* d_ws, size_t ws_size,
                              hipStream_t stream) {
    const float* feat = (const float*)d_in[0];  // [8,1024,64]
    const float* geom = (const float*)d_in[1];  // [8,1024,3]
    const float* W    = (const float*)d_in[2];  // [3,64,64]
    float* out        = (float*)d_out;          // [8,1024,64]

    const int nblocks = BATCHSZ * NPTS / PPB;   // 1024 blocks x 512 threads
    neigh_conv_kernel<<<nblocks, BS, 0, stream>>>(feat, geom, W, out);
}

// Round 13
// 18.269 us; speedup vs baseline: 1.1508x; 1.1508x over previous
//
#include <hip/hip_runtime.h>

// NeighborsConvolution: out[z,a,i] = sum_{b,x,j} [|r_b-r_a|<0.5] * (r_b-r_a)_x * W[x,i,j] * feat[z,b,j]
// B=8, N=1024, CIN=COUT=64.
//
// R13 = R10 (best, 18.3us) + depth-2 software-pipelined process loop.
// R12's lesson: per-neighbor bookkeeping in the walk loop is a net loss.
// Here the pipeline adds ZERO selects/counters: two pending (b,f) pairs as
// named registers, shifted each iteration; the feat load for the newest
// neighbor issues before the oldest is consumed (2 loads in flight).
// Consume order stays ascending-b -> arithmetic bit-identical to R10.
//
// Everything else identical to R10: single kernel, chunked swizzled W-LDS
// pickup through the dead red region, SGPR mask-scan, xj-split epilogue.

#define BATCHSZ 8
#define NPTS 1024
#define CIN 64
#define COUT 64
#define NXJ (3 * CIN)      // 192
#define NG (NXJ / 4)       // 48 float4 groups
#define PPB 8              // points (waves) per block
#define BS (PPB * 64)      // 512
#define GPW (NG / PPB)     // 6 W-groups per wave
#define NSTEP (NPTS / 64)  // 16 ballot steps

typedef float f32x2 __attribute__((ext_vector_type(2)));

// smem layout (floats):
//  [0,3072)     geo (12KB)                 live: stage -> end of process
//  [3072,7168)  wstage / red (16KB)        live: prologue staging, then epilogue red
//  [7168,8704)  tmp[8][192] (6KB)
#define SM_RED 3072
#define SM_TMP 7168
#define SM_TOTAL 8704

__global__ __launch_bounds__(BS, 8) void neigh_conv_kernel(
    const float* __restrict__ feat,  // [B,N,CIN]
    const float* __restrict__ geom,  // [B,N,3]
    const float* __restrict__ W,     // [3,COUT,CIN]
    float* __restrict__ out)         // [B,N,COUT]
{
    const int lane = threadIdx.x & 63;
    const int wv   = threadIdx.x >> 6;
    const int p    = blockIdx.x * PPB + wv;
    const int a    = p & (NPTS - 1);
    const int z    = p >> 10;        // uniform across block (8 | 1024)

    __shared__ __align__(16) float smem[SM_TOTAL];

    // ---- stage geometry (coalesced float4) ----
    {
        const float4* src = (const float4*)(geom + (size_t)z * NPTS * 3);
        float4* dst = (float4*)smem;
        for (int k = threadIdx.x; k < NPTS * 3 / 4; k += BS)
            dst[k] = src[k];
    }

    // ---- W fragment pickup via chunked LDS staging (16KB per x-chunk) ----
    // wr[q] = { W[x][lane][4c+e], e=0..3 }  with g = 6*wv+q, x = g>>4, c = g&15
    const int g0 = wv * GPW;
    float4 wr[GPW];
    {
        const float4* w4 = (const float4*)W;          // [3][1024] float4
        float4* ws = (float4*)(smem + SM_RED);        // 1024 float4
        for (int x = 0; x < 3; ++x) {
            __syncthreads();  // x=0: geo done; x>0: prev pickups done
            // stage chunk x, XOR-rotate swizzle: k=(i*16+j4) -> i*16+((j4+i)&15)
            #pragma unroll
            for (int kk = 0; kk < 2; ++kk) {
                const int k = threadIdx.x + kk * BS;
                const int idx = (k & ~15) | ((k + (k >> 4)) & 15);
                ws[idx] = w4[x * 1024 + k];           // coalesced global read
            }
            __syncthreads();
            #pragma unroll
            for (int q = 0; q < GPW; ++q) {
                const int g = g0 + q;
                if ((g >> 4) == x) {                  // wave-uniform
                    const int c = g & 15;
                    wr[q] = ws[(lane << 4) | ((c + lane) & 15)];  // conflict-free
                }
            }
        }
    }

    const float* geo = smem;
    const float gax = geo[a * 3 + 0];
    const float gay = geo[a * 3 + 1];
    const float gaz = geo[a * 3 + 2];
    const float* fz = feat + (size_t)z * NPTS * CIN;

    // ---- scan: 16 ballot steps; masks live wave-uniform (SGPR pairs) ----
    unsigned long long masks[NSTEP];
    #pragma unroll
    for (int ss = 0; ss < NSTEP; ++ss) {
        const int b = ss * 64 + lane;
        float d2;
        {
            // Bit-exact vs numpy near boundary: no contraction, left-assoc.
            #pragma clang fp contract(off)
            const float dx = geo[b * 3 + 0] - gax;   // stride-3: conflict-free
            const float dy = geo[b * 3 + 1] - gay;
            const float dz = geo[b * 3 + 2] - gaz;
            d2 = dx * dx + dy * dy + dz * dz;
        }
        masks[ss] = __ballot(d2 < 0.25f);
    }

    // ---- process: depth-2 pipelined mask-walk (2 feat loads in flight) ----
    float acc0 = 0.f, acc1 = 0.f, acc2 = 0.f;
    int   b1 = -1, b2 = -1;      // b1 = newest pending, b2 = oldest pending
    float f1 = 0.f, f2 = 0.f;

    auto consume = [&](int bc, float fc) {
        const float gbx = geo[bc * 3 + 0];   // uniform addr -> LDS broadcast
        const float gby = geo[bc * 3 + 1];
        const float gbz = geo[bc * 3 + 2];
        const float dx = gbx - gax;          // bit-identical to scan's diff
        const float dy = gby - gay;
        const float dz = gbz - gaz;
        acc0 = fmaf(dx, fc, acc0);
        acc1 = fmaf(dy, fc, acc1);
        acc2 = fmaf(dz, fc, acc2);
    };

    #pragma unroll
    for (int ss = 0; ss < NSTEP; ++ss) {
        unsigned long long mm = masks[ss];
        while (mm) {                     // wave-uniform scalar walk
            const int src = __ffsll(mm) - 1;
            mm &= mm - 1ull;
            const int b = ss * 64 + src;
            const float f = fz[(size_t)b * CIN + lane];  // issue load NOW
            if (b2 >= 0) consume(b2, f2);   // consume oldest (load landed)
            b2 = b1; f2 = f1;               // shift pipeline (reg moves only)
            b1 = b;  f1 = f;
        }
    }
    if (b2 >= 0) consume(b2, f2);        // drain (ascending order preserved)
    if (b1 >= 0) consume(b1, f1);

    float* tmp = smem + SM_TMP + wv * NXJ;
    tmp[0 * CIN + lane] = acc0;
    tmp[1 * CIN + lane] = acc1;
    tmp[2 * CIN + lane] = acc2;
    __syncthreads();   // pickups done, tmp visible; red free to write

    // ---- epilogue: wave wv owns W groups [6wv,6wv+6), all 8 points ----
    float* red = smem + SM_RED;   // red[wv*8+pp][i]
    #pragma unroll
    for (int pp = 0; pp < PPB; ++pp) {
        const float4* t4 = (const float4*)(smem + SM_TMP + pp * NXJ);
        f32x2 facc = {0.f, 0.f};
        #pragma unroll
        for (int q = 0; q < GPW; ++q) {
            const float4 t = t4[g0 + q];          // uniform -> LDS broadcast
            f32x2 ta; ta.x = t.x; ta.y = t.y;
            f32x2 tb; tb.x = t.z; tb.y = t.w;
            f32x2 wa; wa.x = wr[q].x; wa.y = wr[q].y;
            f32x2 wb; wb.x = wr[q].z; wb.y = wr[q].w;
            facc = ta * wa + facc;                // v_pk_fma_f32
            facc = tb * wb + facc;
        }
        red[(wv * PPB + pp) * COUT + lane] = facc.x + facc.y;
    }
    __syncthreads();

    float o = 0.f;
    #pragma unroll
    for (int w = 0; w < PPB; ++w)
        o += red[(w * PPB + wv) * COUT + lane];   // 2 lanes/bank: free

    out[(size_t)p * COUT + lane] = o;
}

extern "C" void kernel_launch(void* const* d_in, const int* in_sizes, int n_in,
                              void* d_out, int out_size, void* d_ws, size_t ws_size,
                              hipStream_t stream) {
    const float* feat = (const float*)d_in[0];  // [8,1024,64]
    const float* geom = (const float*)d_in[1];  // [8,1024,3]
    const float* W    = (const float*)d_in[2];  // [3,64,64]
    float* out        = (float*)d_out;          // [8,1024,64]

    const int nblocks = BATCHSZ * NPTS / PPB;   // 1024 blocks x 512 threads
    neigh_conv_kernel<<<nblocks, BS, 0, stream>>>(feat, geom, W, out);
}